// Round 4
// baseline (244.563 us; speedup 1.0000x reference)
//
#include <hip/hip_runtime.h>
#include <hip/hip_bf16.h>

typedef short bf16x8 __attribute__((ext_vector_type(8)));   // 8 bf16 = 4 VGPRs
typedef float f32x4  __attribute__((ext_vector_type(4)));
typedef unsigned int u32x4 __attribute__((ext_vector_type(4)));

#define SPATIAL 35
#define K1 350
#define KPAD 352          // 11 chunks of 32
#define N1 256
#define TILE_M 64
#define NCHUNK 11
#define ATHIRD 128        // k-elems per third buffer (4 chunks)

// ---- pre-kernel: w1 [256][350] f32 -> chunk-major bf16 w1t[ch][n][32] ----
__global__ void convert_w1(const float* __restrict__ w1, unsigned short* __restrict__ w1t) {
    int i  = blockIdx.x * 256 + threadIdx.x;    // < 256*352 = 90112
    int kk = i & 31;
    int n  = (i >> 5) & 255;
    int ch = i >> 13;
    int k  = ch * 32 + kk;
    float v = (k < K1) ? w1[n * K1 + k] : 0.f;
    w1t[i] = __builtin_bit_cast(unsigned short, __float2bfloat16(v));
}

__global__ __launch_bounds__(256, 4)
void fused_actor_critic_mfma3(const float* __restrict__ state,
                              const float* __restrict__ wa, const float* __restrict__ ba,
                              const unsigned short* __restrict__ w1t, const float* __restrict__ b1,
                              const float* __restrict__ w2, const float* __restrict__ b2,
                              const float* __restrict__ wc, const float* __restrict__ bc,
                              const float* __restrict__ wlc, const float* __restrict__ blc,
                              float* __restrict__ out, int batch)
{
    __shared__ __align__(16) unsigned short s_A[TILE_M * ATHIRD];   // 16384 B, swizzled granules
    __shared__ __align__(16) float s_state[TILE_M * SPATIAL];       // 8960 B
    __shared__ __align__(16) float s_part[1536];                    // 6144 B: FC2 partials + critic
    // total 31488 B -> 4-5 blocks/CU

    const int t    = threadIdx.x;
    const int lane = t & 63;
    const int wave = t >> 6;
    const int lm   = lane & 15;
    const int lq   = lane >> 4;
    const int s_base = blockIdx.x * TILE_M;
    const int n0w  = wave * 64;

    // ---- W prefetch: chunks 0,1 (contiguous 1KB/instr, L2-resident) ----
    bf16x8 wf[2][4];
    const unsigned short* wrow = w1t + (size_t)(n0w + lm) * 32 + lq * 8;
    #pragma unroll
    for (int nt = 0; nt < 4; ++nt) wf[0][nt] = *(const bf16x8*)(wrow + nt * 512);
    #pragma unroll
    for (int nt = 0; nt < 4; ++nt) wf[1][nt] = *(const bf16x8*)(wrow + 8192 + nt * 512);

    // ---- stage state tile -> LDS, coalesced ----
    {
        const float* src = state + (size_t)s_base * SPATIAL;
        #pragma unroll
        for (int r = 0; r < 9; ++r) {
            int idx = t + r * 256;
            if (idx < TILE_M * SPATIAL) s_state[idx] = src[idx];
        }
    }

    f32x4 acc[4][4];                 // [nt][mt]; neuron = n0w+16nt+4lq+r, sample = 16mt+lm
    #pragma unroll
    for (int nt = 0; nt < 4; ++nt)
        #pragma unroll
        for (int mt = 0; mt < 4; ++mt)
            acc[nt][mt] = (f32x4){0.f, 0.f, 0.f, 0.f};

    __syncthreads();

    // ---- 3 thirds: conv(chunk=wave) -> barrier -> MFMA -> barrier ----
    #pragma unroll
    for (int third = 0; third < 3; ++third) {
        const int ch_cv = third * 4 + wave;          // this wave converts one chunk
        if (ch_cv < NCHUNK) {
            const float* srow = s_state + lane * SPATIAL;
            #pragma unroll
            for (int p = 0; p < 4; ++p) {
                unsigned int dw[4];
                #pragma unroll
                for (int q = 0; q < 4; ++q) {
                    float h[2];
                    #pragma unroll
                    for (int e = 0; e < 2; ++e) {
                        int k = ch_cv * 32 + p * 8 + q * 2 + e;   // wave-uniform
                        float v = 0.f;
                        if (k < K1) {
                            int c  = (k * 469) >> 14;             // k/35, exact for k<350
                            int ij = k - c * 35;
                            v = fmaxf(fmaf(srow[ij], wa[c], ba[c]), 0.f);
                        }
                        h[e] = v;
                    }
                    unsigned int u0 = (unsigned int)__builtin_bit_cast(unsigned short, __float2bfloat16(h[0]));
                    unsigned int u1 = (unsigned int)__builtin_bit_cast(unsigned short, __float2bfloat16(h[1]));
                    dw[q] = u0 | (u1 << 16);
                }
                int g = (wave * 4 + p) ^ (lane & 7);              // granule swizzle
                ((u32x4*)s_A)[lane * 16 + g] = (u32x4){dw[0], dw[1], dw[2], dw[3]};
            }
        }
        __syncthreads();

        const int nch = (third < 2) ? 4 : 3;
        #pragma unroll
        for (int cl = 0; cl < 4; ++cl) {
            if (cl >= nch) break;
            const int ch  = third * 4 + cl;
            const int cur = ch & 1;
            bf16x8 af[4];
            #pragma unroll
            for (int mt = 0; mt < 4; ++mt) {
                int row = 16 * mt + lm;
                int g   = (cl * 4 + lq) ^ (lm & 7);
                af[mt] = *(const bf16x8*)(s_A + row * ATHIRD + g * 8);
            }
            #pragma unroll
            for (int nt = 0; nt < 4; ++nt)
                #pragma unroll
                for (int mt = 0; mt < 4; ++mt)
                    acc[nt][mt] = __builtin_amdgcn_mfma_f32_16x16x32_bf16(
                        wf[cur][nt], af[mt], acc[nt][mt], 0, 0, 0);
            if (ch + 2 < NCHUNK) {
                #pragma unroll
                for (int nt = 0; nt < 4; ++nt)
                    wf[cur][nt] = *(const bf16x8*)(wrow + (size_t)(ch + 2) * 8192 + nt * 512);
            }
        }
        if (third < 2) __syncthreads();      // protect s_A before next conv overwrites
    }

    // ---- critic partial (s_state still valid) ----
    float cv = 0.f;
    {
        const int ij0 = wave * 9;
        const int nij = (wave < 3) ? 9 : 8;
        const float* srow = s_state + lane * SPATIAL;
        #pragma unroll
        for (int u = 0; u < 9; ++u) {
            if (u < nij) {
                int ij = ij0 + u;
                float x = srow[ij];
                #pragma unroll
                for (int c = 0; c < 3; ++c)
                    cv = fmaf(wlc[c * SPATIAL + ij], fmaxf(fmaf(x, wc[c], bc[c]), 0.f), cv);
            }
        }
    }

    // ---- bias + relu ----
    #pragma unroll
    for (int nt = 0; nt < 4; ++nt) {
        f32x4 bv = *(const f32x4*)&b1[n0w + 16 * nt + 4 * lq];
        #pragma unroll
        for (int mt = 0; mt < 4; ++mt)
            #pragma unroll
            for (int r = 0; r < 4; ++r)
                acc[nt][mt][r] = fmaxf(acc[nt][mt][r] + bv[r], 0.f);
    }

    // ---- FC2: reduce over lq (2 shfl steps), partials to s_part ----
    float* part = s_part;            // [wave][m][l] : wave*320 + m*5 + l
    float* crit = s_part + 1280;     // [wave][s]    : wave*64 + s
    #pragma unroll
    for (int l = 0; l < 5; ++l) {
        f32x4 wv[4];
        #pragma unroll
        for (int nt = 0; nt < 4; ++nt)
            wv[nt] = *(const f32x4*)&w2[l * N1 + n0w + 16 * nt + 4 * lq];
        #pragma unroll
        for (int mt = 0; mt < 4; ++mt) {
            float p = 0.f;
            #pragma unroll
            for (int nt = 0; nt < 4; ++nt)
                #pragma unroll
                for (int r = 0; r < 4; ++r)
                    p = fmaf(acc[nt][mt][r], wv[nt][r], p);
            p += __shfl_xor(p, 16);
            p += __shfl_xor(p, 32);
            bool mine = (l < 4) ? (lq == l) : (lq == 0);
            if (mine) part[wave * 320 + (16 * mt + lm) * 5 + l] = p;
        }
    }
    crit[wave * 64 + lane] = cv;
    __syncthreads();

    // ---- final combine ----
    if (t < TILE_M) {
        const int gs = s_base + t;
        #pragma unroll
        for (int l = 0; l < 5; ++l) {
            float v = part[t * 5 + l] + part[320 + t * 5 + l]
                    + part[640 + t * 5 + l] + part[960 + t * 5 + l] + b2[l];
            out[(size_t)gs * 5 + l] = v;
        }
    } else if (t < 128) {
        const int s = t - 64;
        float v = crit[s] + crit[64 + s] + crit[128 + s] + crit[192 + s] + blc[0];
        out[(size_t)5 * batch + s_base + s] = v;
    }
}

extern "C" void kernel_launch(void* const* d_in, const int* in_sizes, int n_in,
                              void* d_out, int out_size, void* d_ws, size_t ws_size,
                              hipStream_t stream) {
    const float* state = (const float*)d_in[0];
    const float* wa    = (const float*)d_in[1];
    const float* ba    = (const float*)d_in[2];
    const float* w1    = (const float*)d_in[3];
    const float* b1    = (const float*)d_in[4];
    const float* w2    = (const float*)d_in[5];
    const float* b2    = (const float*)d_in[6];
    const float* wc    = (const float*)d_in[7];
    const float* bc    = (const float*)d_in[8];
    const float* wlc   = (const float*)d_in[9];
    const float* blc   = (const float*)d_in[10];
    float* out = (float*)d_out;
    unsigned short* w1t = (unsigned short*)d_ws;     // 256*352*2 = 180224 B

    int B = in_sizes[0] / SPATIAL;                   // 262144
    hipLaunchKernelGGL(convert_w1, dim3((N1 * KPAD) / 256), dim3(256), 0, stream, w1, w1t);
    hipLaunchKernelGGL(fused_actor_critic_mfma3, dim3(B / TILE_M), dim3(256), 0, stream,
                       state, wa, ba, w1t, b1, w2, b2, wc, bc, wlc, blc, out, B);
}

// Round 5
// 191.560 us; speedup vs baseline: 1.2767x; 1.2767x over previous
//
#include <hip/hip_runtime.h>
#include <hip/hip_bf16.h>

typedef short bf16x8 __attribute__((ext_vector_type(8)));   // 8 bf16 = 4 VGPRs
typedef float f32x4  __attribute__((ext_vector_type(4)));
typedef unsigned int u32x4 __attribute__((ext_vector_type(4)));

#define SPATIAL 35
#define K1 350
#define KPAD 352          // 11 chunks of 32
#define N1 256
#define TILE_M 64
#define NCHUNK 11

// ---- pre-kernel: w1 -> chunk-major bf16 w1t[ch][n][32]; (wa,ba) -> per-k coef table ----
__global__ void prep_tables(const float* __restrict__ w1,
                            const float* __restrict__ wa, const float* __restrict__ ba,
                            unsigned short* __restrict__ w1t, float* __restrict__ coef) {
    int i  = blockIdx.x * 256 + threadIdx.x;    // < 256*352 = 90112
    int kk = i & 31;
    int n  = (i >> 5) & 255;
    int ch = i >> 13;
    int k  = ch * 32 + kk;
    float v = (k < K1) ? w1[n * K1 + k] : 0.f;
    w1t[i] = __builtin_bit_cast(unsigned short, __float2bfloat16(v));
    if (i < KPAD) {
        float w = 0.f, b = 0.f;
        if (i < K1) { int c = i / SPATIAL; w = wa[c]; b = ba[c]; }
        coef[2 * i]     = w;
        coef[2 * i + 1] = b;
    }
}

__global__ __launch_bounds__(256, 3)
void fused_actor_critic_mfma4(const float* __restrict__ state,
                              const float* __restrict__ coef_g,
                              const unsigned short* __restrict__ w1t, const float* __restrict__ b1,
                              const float* __restrict__ w2, const float* __restrict__ b2,
                              const float* __restrict__ wc, const float* __restrict__ bc,
                              const float* __restrict__ wlc, const float* __restrict__ blc,
                              float* __restrict__ out, int batch)
{
    __shared__ __align__(16) float s_state[TILE_M * SPATIAL];   // 8960 B
    __shared__ __align__(16) float s_coef[2 * KPAD];            // 2816 B (float2[k] = wa[c],ba[c])
    __shared__ __align__(16) float s_part[1536];                // 6144 B
    // total 17920 B

    const int t    = threadIdx.x;
    const int lane = t & 63;
    const int wave = t >> 6;
    const int lm   = lane & 15;
    const int lq   = lane >> 4;
    const int s_base = blockIdx.x * TILE_M;
    const int n0w  = wave * 64;

    // ---- W prefetch: chunks 0,1 (contiguous 1KB/instr, L2-resident) ----
    bf16x8 wf[2][4];
    const unsigned short* wrow = w1t + (size_t)(n0w + lm) * 32 + lq * 8;
    #pragma unroll
    for (int nt = 0; nt < 4; ++nt) wf[0][nt] = *(const bf16x8*)(wrow + nt * 512);
    #pragma unroll
    for (int nt = 0; nt < 4; ++nt) wf[1][nt] = *(const bf16x8*)(wrow + 8192 + nt * 512);

    // ---- stage state tile + coef table -> LDS (coalesced); ONE barrier ----
    {
        const float* src = state + (size_t)s_base * SPATIAL;
        #pragma unroll
        for (int r = 0; r < 9; ++r) {
            int idx = t + r * 256;
            if (idx < TILE_M * SPATIAL) s_state[idx] = src[idx];
        }
        #pragma unroll
        for (int r = 0; r < 3; ++r) {
            int idx = t + r * 256;
            if (idx < 2 * KPAD) s_coef[idx] = coef_g[idx];
        }
    }

    f32x4 acc[4][4];                 // [nt][mt]; neuron = n0w+16nt+4lq+r, sample = 16mt+lm
    #pragma unroll
    for (int nt = 0; nt < 4; ++nt)
        #pragma unroll
        for (int mt = 0; mt < 4; ++mt)
            acc[nt][mt] = (f32x4){0.f, 0.f, 0.f, 0.f};

    __syncthreads();

    // ---- barrier-free K loop: per-wave A-fragment build + MFMA ----
    const int kb = lq * 8;
    const float* srow0 = s_state + lm * SPATIAL;     // +560 per mt (16*35)
    const float2* cf = (const float2*)s_coef;

    #pragma unroll
    for (int ch = 0; ch < NCHUNK; ++ch) {
        const int cur = ch & 1;
        unsigned int aw[4][4];                       // [mt][jp]
        const int k0 = ch * 32 + kb;
        #pragma unroll
        for (int jp = 0; jp < 4; ++jp) {
            const int ka = k0 + 2 * jp;
            float2 c0 = cf[ka];                      // broadcast ds_read (4 addrs/wave)
            float2 c1 = cf[ka + 1];
            int ij0 = ka - ((ka * 469) >> 14) * SPATIAL;       // ka mod 35 (exact, ka<=351)
            int ij1 = (ka + 1) - (((ka + 1) * 469) >> 14) * SPATIAL;
            #pragma unroll
            for (int mt = 0; mt < 4; ++mt) {
                float x0 = srow0[mt * 560 + ij0];
                float x1 = srow0[mt * 560 + ij1];
                float h0 = fmaxf(fmaf(x0, c0.x, c0.y), 0.f);
                float h1 = fmaxf(fmaf(x1, c1.x, c1.y), 0.f);
                unsigned int u0 = (unsigned int)__builtin_bit_cast(unsigned short, __float2bfloat16(h0));
                unsigned int u1 = (unsigned int)__builtin_bit_cast(unsigned short, __float2bfloat16(h1));
                aw[mt][jp] = u0 | (u1 << 16);
            }
        }
        bf16x8 af[4];
        #pragma unroll
        for (int mt = 0; mt < 4; ++mt)
            af[mt] = __builtin_bit_cast(bf16x8, (u32x4){aw[mt][0], aw[mt][1], aw[mt][2], aw[mt][3]});
        #pragma unroll
        for (int nt = 0; nt < 4; ++nt)
            #pragma unroll
            for (int mt = 0; mt < 4; ++mt)
                acc[nt][mt] = __builtin_amdgcn_mfma_f32_16x16x32_bf16(
                    wf[cur][nt], af[mt], acc[nt][mt], 0, 0, 0);
        if (ch + 2 < NCHUNK) {
            #pragma unroll
            for (int nt = 0; nt < 4; ++nt)
                wf[cur][nt] = *(const bf16x8*)(wrow + (size_t)(ch + 2) * 8192 + nt * 512);
        }
    }

    // ---- critic partial (s_state still valid; no barrier needed to read it) ----
    float cv = 0.f;
    {
        const int ij0 = wave * 9;
        const int nij = (wave < 3) ? 9 : 8;
        const float* srow = s_state + lane * SPATIAL;
        #pragma unroll
        for (int u = 0; u < 9; ++u) {
            if (u < nij) {
                int ij = ij0 + u;
                float x = srow[ij];
                #pragma unroll
                for (int c = 0; c < 3; ++c)
                    cv = fmaf(wlc[c * SPATIAL + ij], fmaxf(fmaf(x, wc[c], bc[c]), 0.f), cv);
            }
        }
    }

    // ---- bias + relu ----
    #pragma unroll
    for (int nt = 0; nt < 4; ++nt) {
        f32x4 bv = *(const f32x4*)&b1[n0w + 16 * nt + 4 * lq];
        #pragma unroll
        for (int mt = 0; mt < 4; ++mt)
            #pragma unroll
            for (int r = 0; r < 4; ++r)
                acc[nt][mt][r] = fmaxf(acc[nt][mt][r] + bv[r], 0.f);
    }

    // ---- FC2: reduce over lq (2 shfl steps), partials to s_part ----
    float* part = s_part;            // [wave][m][l] : wave*320 + m*5 + l
    float* crit = s_part + 1280;     // [wave][s]    : wave*64 + s
    #pragma unroll
    for (int l = 0; l < 5; ++l) {
        f32x4 wv[4];
        #pragma unroll
        for (int nt = 0; nt < 4; ++nt)
            wv[nt] = *(const f32x4*)&w2[l * N1 + n0w + 16 * nt + 4 * lq];
        #pragma unroll
        for (int mt = 0; mt < 4; ++mt) {
            float p = 0.f;
            #pragma unroll
            for (int nt = 0; nt < 4; ++nt)
                #pragma unroll
                for (int r = 0; r < 4; ++r)
                    p = fmaf(acc[nt][mt][r], wv[nt][r], p);
            p += __shfl_xor(p, 16);
            p += __shfl_xor(p, 32);
            bool mine = (l < 4) ? (lq == l) : (lq == 0);
            if (mine) part[wave * 320 + (16 * mt + lm) * 5 + l] = p;
        }
    }
    crit[wave * 64 + lane] = cv;
    __syncthreads();

    // ---- final combine ----
    if (t < TILE_M) {
        const int gs = s_base + t;
        #pragma unroll
        for (int l = 0; l < 5; ++l) {
            float v = part[t * 5 + l] + part[320 + t * 5 + l]
                    + part[640 + t * 5 + l] + part[960 + t * 5 + l] + b2[l];
            out[(size_t)gs * 5 + l] = v;
        }
    } else if (t < 128) {
        const int s = t - 64;
        float v = crit[s] + crit[64 + s] + crit[128 + s] + crit[192 + s] + blc[0];
        out[(size_t)5 * batch + s_base + s] = v;
    }
}

extern "C" void kernel_launch(void* const* d_in, const int* in_sizes, int n_in,
                              void* d_out, int out_size, void* d_ws, size_t ws_size,
                              hipStream_t stream) {
    const float* state = (const float*)d_in[0];
    const float* wa    = (const float*)d_in[1];
    const float* ba    = (const float*)d_in[2];
    const float* w1    = (const float*)d_in[3];
    const float* b1    = (const float*)d_in[4];
    const float* w2    = (const float*)d_in[5];
    const float* b2    = (const float*)d_in[6];
    const float* wc    = (const float*)d_in[7];
    const float* bc    = (const float*)d_in[8];
    const float* wlc   = (const float*)d_in[9];
    const float* blc   = (const float*)d_in[10];
    float* out = (float*)d_out;
    unsigned short* w1t = (unsigned short*)d_ws;            // 180224 B
    float* coef = (float*)((char*)d_ws + 180224);           // 2816 B (float2[352])

    int B = in_sizes[0] / SPATIAL;                          // 262144
    hipLaunchKernelGGL(prep_tables, dim3((N1 * KPAD) / 256), dim3(256), 0, stream,
                       w1, wa, ba, w1t, coef);
    hipLaunchKernelGGL(fused_actor_critic_mfma4, dim3(B / TILE_M), dim3(256), 0, stream,
                       state, coef, w1t, b1, w2, b2, wc, bc, wlc, blc, out, B);
}

// Round 6
// 185.918 us; speedup vs baseline: 1.3154x; 1.0303x over previous
//
#include <hip/hip_runtime.h>
#include <hip/hip_bf16.h>

typedef short bf16x8 __attribute__((ext_vector_type(8)));   // 8 bf16 = 4 VGPRs
typedef float f32x4  __attribute__((ext_vector_type(4)));
typedef unsigned int u32x4 __attribute__((ext_vector_type(4)));

#define SPATIAL 35
#define K1 350
#define KPAD 352          // 11 chunks of 32
#define N1 256
#define TILE_M 64
#define NCHUNK 11
#define SROW 36           // padded state row (dwords) -> 16B-aligned rows
#define ABUF_DW 1280      // 64 samples * 20 dwords (16 used + 4 pad)

// ---- pre-kernel: w1 [256][350] f32 -> chunk-major bf16 w1t[ch][n][32] ----
__global__ void convert_w1(const float* __restrict__ w1, unsigned short* __restrict__ w1t) {
    int i  = blockIdx.x * 256 + threadIdx.x;    // < 256*352 = 90112
    int kk = i & 31;
    int n  = (i >> 5) & 255;
    int ch = i >> 13;
    int k  = ch * 32 + kk;
    float v = (k < K1) ? w1[n * K1 + k] : 0.f;
    w1t[i] = __builtin_bit_cast(unsigned short, __float2bfloat16(v));
}

// conv of one 32-k chunk for this lane's sample (x in regs, ch becomes literal after unroll)
static __device__ __forceinline__ void conv_chunk(int ch, int buf, const float* __restrict__ x,
                                                  const float* __restrict__ wa, const float* __restrict__ ba,
                                                  unsigned int* __restrict__ s_abuf, int lane) {
    unsigned int* ab = s_abuf + buf * ABUF_DW + lane * 20;
    u32x4 g[4];
    #pragma unroll
    for (int d = 0; d < 16; ++d) {
        const int k0 = ch * 32 + 2 * d;
        const int k1 = k0 + 1;
        float h0 = 0.f, h1 = 0.f;
        if (k0 < K1) { const int c = k0 / SPATIAL, ij = k0 % SPATIAL;   // folds: ch literal
                       h0 = fmaxf(fmaf(x[ij], wa[c], ba[c]), 0.f); }
        if (k1 < K1) { const int c = k1 / SPATIAL, ij = k1 % SPATIAL;
                       h1 = fmaxf(fmaf(x[ij], wa[c], ba[c]), 0.f); }
        unsigned int u0 = (unsigned int)__builtin_bit_cast(unsigned short, __float2bfloat16(h0));
        unsigned int u1 = (unsigned int)__builtin_bit_cast(unsigned short, __float2bfloat16(h1));
        g[d >> 2][d & 3] = u0 | (u1 << 16);
    }
    #pragma unroll
    for (int gg = 0; gg < 4; ++gg)
        reinterpret_cast<u32x4*>(ab)[gg] = g[gg];         // 4x b128, bank-balanced (stride 20)
}

__global__ __launch_bounds__(256, 3)
void fused_actor_critic_mfma5(const float* __restrict__ state,
                              const float* __restrict__ wa, const float* __restrict__ ba,
                              const unsigned short* __restrict__ w1t, const float* __restrict__ b1,
                              const float* __restrict__ w2, const float* __restrict__ b2,
                              const float* __restrict__ wc, const float* __restrict__ bc,
                              const float* __restrict__ wlc, const float* __restrict__ blc,
                              float* __restrict__ out, int batch)
{
    __shared__ __align__(16) float        s_state[TILE_M * SROW];   // 9216 B
    __shared__ __align__(16) unsigned int s_abuf[2 * ABUF_DW];      // 10240 B
    __shared__ __align__(16) float        s_part[1280];             // 5120 B   (total 24576 B)

    const int t    = threadIdx.x;
    const int lane = t & 63;
    const int wave = t >> 6;
    const int lm   = lane & 15;
    const int lq   = lane >> 4;
    const int s_base = blockIdx.x * TILE_M;
    const int n0w  = wave * 64;

    // ---- W prefetch: chunks 0,1 (contiguous 1KB/instr, L2-resident) ----
    bf16x8 wf[2][4];
    const unsigned short* wrow = w1t + (size_t)(n0w + lm) * 32 + lq * 8;
    #pragma unroll
    for (int nt = 0; nt < 4; ++nt) wf[0][nt] = *(const bf16x8*)(wrow + nt * 512);
    #pragma unroll
    for (int nt = 0; nt < 4; ++nt) wf[1][nt] = *(const bf16x8*)(wrow + 8192 + nt * 512);

    // ---- stage state tile -> LDS (coalesced read, padded-row scatter write) ----
    {
        const float* src = state + (size_t)s_base * SPATIAL;
        #pragma unroll
        for (int r = 0; r < 9; ++r) {
            int idx = t + r * 256;
            if (idx < TILE_M * SPATIAL) {
                int s  = (int)(((unsigned)idx * 59919u) >> 21);    // idx/35, exact for idx<2240
                int ij = idx - s * SPATIAL;
                s_state[s * SROW + ij] = src[idx];
            }
        }
    }
    __syncthreads();

    // ---- own sample row -> registers (one-time; lane = sample, all waves) ----
    float x[SPATIAL];
    {
        const float* row = s_state + lane * SROW;
        #pragma unroll
        for (int ij = 0; ij < 32; ij += 4)
            *reinterpret_cast<f32x4*>(&x[ij]) = *reinterpret_cast<const f32x4*>(&row[ij]);
        x[32] = row[32]; x[33] = row[33]; x[34] = row[34];
    }

    f32x4 acc[4][4];                 // [nt][mt]; neuron = n0w+16nt+4lq+r, sample = 16mt+lm
    #pragma unroll
    for (int nt = 0; nt < 4; ++nt)
        #pragma unroll
        for (int mt = 0; mt < 4; ++mt)
            acc[nt][mt] = (f32x4){0.f, 0.f, 0.f, 0.f};

    // ---- prologue: wave0 converts chunk 0 ----
    if (wave == 0) conv_chunk(0, 0, x, wa, ba, s_abuf, lane);
    __syncthreads();

    // ---- depth-1 pipelined K loop: conv(ch+1) on owner wave || MFMA(ch) on all ----
    #pragma unroll
    for (int ch = 0; ch < NCHUNK; ++ch) {
        if (ch + 1 < NCHUNK && wave == ((ch + 1) & 3))
            conv_chunk(ch + 1, (ch + 1) & 1, x, wa, ba, s_abuf, lane);

        const int cur = ch & 1;
        bf16x8 af[4];
        #pragma unroll
        for (int mt = 0; mt < 4; ++mt)
            af[mt] = *reinterpret_cast<const bf16x8*>(s_abuf + cur * ABUF_DW + (16 * mt + lm) * 20 + lq * 4);
        #pragma unroll
        for (int nt = 0; nt < 4; ++nt)
            #pragma unroll
            for (int mt = 0; mt < 4; ++mt)
                acc[nt][mt] = __builtin_amdgcn_mfma_f32_16x16x32_bf16(
                    wf[cur][nt], af[mt], acc[nt][mt], 0, 0, 0);
        if (ch + 2 < NCHUNK) {
            #pragma unroll
            for (int nt = 0; nt < 4; ++nt)
                wf[cur][nt] = *(const bf16x8*)(wrow + (size_t)(ch + 2) * 8192 + nt * 512);
        }
        __syncthreads();
    }

    // ---- critic: wave3 only, fully in registers (x is this lane's sample row) ----
    if (wave == 3) {
        float cv = blc[0];
        #pragma unroll
        for (int ij = 0; ij < SPATIAL; ++ij)
            #pragma unroll
            for (int c = 0; c < 3; ++c)
                cv = fmaf(wlc[c * SPATIAL + ij], fmaxf(fmaf(x[ij], wc[c], bc[c]), 0.f), cv);
        out[(size_t)5 * batch + s_base + lane] = cv;
    }

    // ---- bias + relu ----
    #pragma unroll
    for (int nt = 0; nt < 4; ++nt) {
        f32x4 bv = *(const f32x4*)&b1[n0w + 16 * nt + 4 * lq];
        #pragma unroll
        for (int mt = 0; mt < 4; ++mt)
            #pragma unroll
            for (int r = 0; r < 4; ++r)
                acc[nt][mt][r] = fmaxf(acc[nt][mt][r] + bv[r], 0.f);
    }

    // ---- FC2: reduce over lq (2 shfl steps), partials to s_part ----
    #pragma unroll
    for (int l = 0; l < 5; ++l) {
        f32x4 wv[4];
        #pragma unroll
        for (int nt = 0; nt < 4; ++nt)
            wv[nt] = *(const f32x4*)&w2[l * N1 + n0w + 16 * nt + 4 * lq];
        #pragma unroll
        for (int mt = 0; mt < 4; ++mt) {
            float p = 0.f;
            #pragma unroll
            for (int nt = 0; nt < 4; ++nt)
                #pragma unroll
                for (int r = 0; r < 4; ++r)
                    p = fmaf(acc[nt][mt][r], wv[nt][r], p);
            p += __shfl_xor(p, 16);
            p += __shfl_xor(p, 32);
            bool mine = (l < 4) ? (lq == l) : (lq == 0);
            if (mine) s_part[wave * 320 + (16 * mt + lm) * 5 + l] = p;
        }
    }
    __syncthreads();

    // ---- final combine ----
    if (t < TILE_M) {
        const int gs = s_base + t;
        #pragma unroll
        for (int l = 0; l < 5; ++l) {
            float v = s_part[t * 5 + l] + s_part[320 + t * 5 + l]
                    + s_part[640 + t * 5 + l] + s_part[960 + t * 5 + l] + b2[l];
            out[(size_t)gs * 5 + l] = v;
        }
    }
}

extern "C" void kernel_launch(void* const* d_in, const int* in_sizes, int n_in,
                              void* d_out, int out_size, void* d_ws, size_t ws_size,
                              hipStream_t stream) {
    const float* state = (const float*)d_in[0];
    const float* wa    = (const float*)d_in[1];
    const float* ba    = (const float*)d_in[2];
    const float* w1    = (const float*)d_in[3];
    const float* b1    = (const float*)d_in[4];
    const float* w2    = (const float*)d_in[5];
    const float* b2    = (const float*)d_in[6];
    const float* wc    = (const float*)d_in[7];
    const float* bc    = (const float*)d_in[8];
    const float* wlc   = (const float*)d_in[9];
    const float* blc   = (const float*)d_in[10];
    float* out = (float*)d_out;
    unsigned short* w1t = (unsigned short*)d_ws;            // 180224 B

    int B = in_sizes[0] / SPATIAL;                          // 262144
    hipLaunchKernelGGL(convert_w1, dim3((N1 * KPAD) / 256), dim3(256), 0, stream, w1, w1t);
    hipLaunchKernelGGL(fused_actor_critic_mfma5, dim3(B / TILE_M), dim3(256), 0, stream,
                       state, wa, ba, w1t, b1, w2, b2, wc, bc, wlc, blc, out, B);
}

// Round 7
// 170.231 us; speedup vs baseline: 1.4367x; 1.0922x over previous
//
#include <hip/hip_runtime.h>
#include <hip/hip_bf16.h>

typedef short bf16x8 __attribute__((ext_vector_type(8)));   // 8 bf16 = 4 VGPRs
typedef float f32x4  __attribute__((ext_vector_type(4)));
typedef unsigned int u32x4 __attribute__((ext_vector_type(4)));

#define SPATIAL 35
#define K1 350
#define KPAD 352          // 11 chunks of 32
#define N1 256
#define TILE_M 64
#define NCHUNK 11
#define HROW 360          // ha row stride in bf16 (352 + 8 pad): 720 B, 16B-aligned, bank-balanced
#define SROW 36           // staging f32 row stride (144 B, 16B-aligned, bank-balanced)

// ---- pre-kernel: w1 [256][350] f32 -> chunk-major bf16 w1t[ch][n][32] ----
__global__ void convert_w1(const float* __restrict__ w1, unsigned short* __restrict__ w1t) {
    int i  = blockIdx.x * 256 + threadIdx.x;    // < 256*352 = 90112
    int kk = i & 31;
    int n  = (i >> 5) & 255;
    int ch = i >> 13;
    int k  = ch * 32 + kk;
    float v = (k < K1) ? w1[n * K1 + k] : 0.f;
    w1t[i] = __builtin_bit_cast(unsigned short, __float2bfloat16(v));
}

// conv of k-band [88W, 88W+88) for this lane's sample; W/g/e compile-time -> c,ij literals
template<int W>
static __device__ __forceinline__ void conv_band(const float* __restrict__ x,
        const float* __restrict__ wa, const float* __restrict__ ba,
        unsigned short* __restrict__ s_ha, int lane) {
    unsigned int* row = reinterpret_cast<unsigned int*>(s_ha + lane * HROW) + 44 * W;
    #pragma unroll
    for (int g = 0; g < 11; ++g) {
        unsigned int dw[4];
        #pragma unroll
        for (int e = 0; e < 4; ++e) {
            const int k0 = 88 * W + 8 * g + 2 * e;
            const int k1 = k0 + 1;
            float h0 = 0.f, h1 = 0.f;
            if (k0 < K1) {
                const int c = k0 / SPATIAL, ij = k0 % SPATIAL;
                h0 = fmaxf(fmaf(x[ij], wa[c], ba[c]), 0.f);
            }
            if (k1 < K1) {
                const int c = k1 / SPATIAL, ij = k1 % SPATIAL;
                h1 = fmaxf(fmaf(x[ij], wa[c], ba[c]), 0.f);
            }
            unsigned int u0 = (unsigned int)__builtin_bit_cast(unsigned short, __float2bfloat16(h0));
            unsigned int u1 = (unsigned int)__builtin_bit_cast(unsigned short, __float2bfloat16(h1));
            dw[e] = u0 | (u1 << 16);
        }
        reinterpret_cast<u32x4*>(row)[g] = (u32x4){dw[0], dw[1], dw[2], dw[3]};
    }
}

__global__ __launch_bounds__(256, 3)
void fused_actor_critic_mfma6(const float* __restrict__ state,
                              const float* __restrict__ wa, const float* __restrict__ ba,
                              const unsigned short* __restrict__ w1t, const float* __restrict__ b1,
                              const float* __restrict__ w2, const float* __restrict__ b2,
                              const float* __restrict__ wc, const float* __restrict__ bc,
                              const float* __restrict__ wlc, const float* __restrict__ blc,
                              float* __restrict__ out, int batch)
{
    __shared__ __align__(16) unsigned short s_ha[TILE_M * HROW];   // 46080 B (staging overlaid)
    __shared__ __align__(16) float s_part[1280];                   // 5120 B   (total 51200 -> 3 blk/CU)

    const int t    = threadIdx.x;
    const int lane = t & 63;
    const int wave = t >> 6;
    const int lm   = lane & 15;
    const int lq   = lane >> 4;
    const int s_base = blockIdx.x * TILE_M;
    const int n0w  = wave * 64;

    // ---- W prefetch: chunks 0,1 (contiguous 1KB/instr, L2-resident) ----
    bf16x8 wfr[2][4];
    const unsigned short* wrow = w1t + (size_t)(n0w + lm) * 32 + lq * 8;
    #pragma unroll
    for (int nt = 0; nt < 4; ++nt) wfr[0][nt] = *(const bf16x8*)(wrow + nt * 512);
    #pragma unroll
    for (int nt = 0; nt < 4; ++nt) wfr[1][nt] = *(const bf16x8*)(wrow + 8192 + nt * 512);

    // ---- stage state tile into s_ha-as-f32 (coalesced read, padded-row write) ----
    {
        float* sst = reinterpret_cast<float*>(s_ha);
        const float* src = state + (size_t)s_base * SPATIAL;
        #pragma unroll
        for (int r = 0; r < 9; ++r) {
            int idx = t + r * 256;
            if (idx < TILE_M * SPATIAL) {
                int s  = (int)(((unsigned)idx * 59919u) >> 21);    // idx/35, exact for idx<2240
                int ij = idx - s * SPATIAL;
                sst[s * SROW + ij] = src[idx];
            }
        }
    }
    __syncthreads();

    // ---- own sample row -> registers (transient; dead before K loop) ----
    float x[36];
    {
        const f32x4* xr = reinterpret_cast<const f32x4*>(
            reinterpret_cast<const float*>(s_ha) + lane * SROW);
        #pragma unroll
        for (int q = 0; q < 9; ++q) *reinterpret_cast<f32x4*>(&x[4 * q]) = xr[q];
    }
    __syncthreads();      // all x loads done before conv overwrites the overlay

    // ---- cooperative conv: wave w owns k-band [88w, 88w+88); wave3 also critic ----
    if      (wave == 0) conv_band<0>(x, wa, ba, s_ha, lane);
    else if (wave == 1) conv_band<1>(x, wa, ba, s_ha, lane);
    else if (wave == 2) conv_band<2>(x, wa, ba, s_ha, lane);
    else {
        conv_band<3>(x, wa, ba, s_ha, lane);
        float cv = blc[0];
        #pragma unroll
        for (int ij = 0; ij < SPATIAL; ++ij)
            #pragma unroll
            for (int c = 0; c < 3; ++c)
                cv = fmaf(wlc[c * SPATIAL + ij], fmaxf(fmaf(x[ij], wc[c], bc[c]), 0.f), cv);
        out[(size_t)5 * batch + s_base + lane] = cv;
    }
    __syncthreads();

    // ---- barrier-free K loop: af depth-1 LDS prefetch, W depth-2 global prefetch ----
    f32x4 acc[4][4];                 // [nt][mt]; neuron = n0w+16nt+4lq+r, sample = 16mt+lm
    #pragma unroll
    for (int nt = 0; nt < 4; ++nt)
        #pragma unroll
        for (int mt = 0; mt < 4; ++mt)
            acc[nt][mt] = (f32x4){0.f, 0.f, 0.f, 0.f};

    const unsigned short* abase = s_ha + lm * HROW + lq * 8;
    bf16x8 afr[2][4];
    #pragma unroll
    for (int mt = 0; mt < 4; ++mt)
        afr[0][mt] = *(const bf16x8*)(abase + mt * 16 * HROW);

    #pragma unroll
    for (int ch = 0; ch < NCHUNK; ++ch) {
        if (ch + 1 < NCHUNK) {
            #pragma unroll
            for (int mt = 0; mt < 4; ++mt)
                afr[(ch + 1) & 1][mt] = *(const bf16x8*)(abase + mt * 16 * HROW + (ch + 1) * 32);
        }
        #pragma unroll
        for (int nt = 0; nt < 4; ++nt)
            #pragma unroll
            for (int mt = 0; mt < 4; ++mt)
                acc[nt][mt] = __builtin_amdgcn_mfma_f32_16x16x32_bf16(
                    wfr[ch & 1][nt], afr[ch & 1][mt], acc[nt][mt], 0, 0, 0);
        if (ch + 2 < NCHUNK) {
            #pragma unroll
            for (int nt = 0; nt < 4; ++nt)
                wfr[ch & 1][nt] = *(const bf16x8*)(wrow + (size_t)(ch + 2) * 8192 + nt * 512);
        }
    }

    // ---- bias + relu ----
    #pragma unroll
    for (int nt = 0; nt < 4; ++nt) {
        f32x4 bv = *(const f32x4*)&b1[n0w + 16 * nt + 4 * lq];
        #pragma unroll
        for (int mt = 0; mt < 4; ++mt)
            #pragma unroll
            for (int r = 0; r < 4; ++r)
                acc[nt][mt][r] = fmaxf(acc[nt][mt][r] + bv[r], 0.f);
    }

    // ---- FC2: reduce over lq (2 shfl steps), partials to s_part ----
    #pragma unroll
    for (int l = 0; l < 5; ++l) {
        f32x4 wv[4];
        #pragma unroll
        for (int nt = 0; nt < 4; ++nt)
            wv[nt] = *(const f32x4*)&w2[l * N1 + n0w + 16 * nt + 4 * lq];
        #pragma unroll
        for (int mt = 0; mt < 4; ++mt) {
            float p = 0.f;
            #pragma unroll
            for (int nt = 0; nt < 4; ++nt)
                #pragma unroll
                for (int r = 0; r < 4; ++r)
                    p = fmaf(acc[nt][mt][r], wv[nt][r], p);
            p += __shfl_xor(p, 16);
            p += __shfl_xor(p, 32);
            bool mine = (l < 4) ? (lq == l) : (lq == 0);
            if (mine) s_part[wave * 320 + (16 * mt + lm) * 5 + l] = p;
        }
    }
    __syncthreads();

    // ---- final combine ----
    if (t < TILE_M) {
        const int gs = s_base + t;
        #pragma unroll
        for (int l = 0; l < 5; ++l) {
            float v = s_part[t * 5 + l] + s_part[320 + t * 5 + l]
                    + s_part[640 + t * 5 + l] + s_part[960 + t * 5 + l] + b2[l];
            out[(size_t)gs * 5 + l] = v;
        }
    }
}

extern "C" void kernel_launch(void* const* d_in, const int* in_sizes, int n_in,
                              void* d_out, int out_size, void* d_ws, size_t ws_size,
                              hipStream_t stream) {
    const float* state = (const float*)d_in[0];
    const float* wa    = (const float*)d_in[1];
    const float* ba    = (const float*)d_in[2];
    const float* w1    = (const float*)d_in[3];
    const float* b1    = (const float*)d_in[4];
    const float* w2    = (const float*)d_in[5];
    const float* b2    = (const float*)d_in[6];
    const float* wc    = (const float*)d_in[7];
    const float* bc    = (const float*)d_in[8];
    const float* wlc   = (const float*)d_in[9];
    const float* blc   = (const float*)d_in[10];
    float* out = (float*)d_out;
    unsigned short* w1t = (unsigned short*)d_ws;            // 180224 B

    int B = in_sizes[0] / SPATIAL;                          // 262144
    hipLaunchKernelGGL(convert_w1, dim3((N1 * KPAD) / 256), dim3(256), 0, stream, w1, w1t);
    hipLaunchKernelGGL(fused_actor_critic_mfma6, dim3(B / TILE_M), dim3(256), 0, stream,
                       state, wa, ba, w1t, b1, w2, b2, wc, bc, wlc, blc, out, B);
}

// Round 8
// 161.432 us; speedup vs baseline: 1.5150x; 1.0545x over previous
//
#include <hip/hip_runtime.h>
#include <hip/hip_bf16.h>

typedef short bf16x8 __attribute__((ext_vector_type(8)));   // 8 bf16 = 4 VGPRs
typedef float f32x4  __attribute__((ext_vector_type(4)));
typedef unsigned int u32x4 __attribute__((ext_vector_type(4)));

#define SPATIAL 35
#define K1 350
#define KPAD 352          // 11 chunks of 32
#define N1 256
#define TILE_M 64
#define NCHUNK 11
#define HROW 360          // ha row stride in bf16 (45 granules): bank-balanced for b128 r/w
#define SROW 36           // staging f32 row stride (16B-aligned, bank-balanced)

// ---- pre-kernel: w1 [256][350] f32 -> chunk-major bf16 w1t[ch][n][32] ----
__global__ void convert_w1(const float* __restrict__ w1, unsigned short* __restrict__ w1t) {
    int i  = blockIdx.x * 256 + threadIdx.x;    // < 256*352 = 90112
    int kk = i & 31;
    int n  = (i >> 5) & 255;
    int ch = i >> 13;
    int k  = ch * 32 + kk;
    float v = (k < K1) ? w1[n * K1 + k] : 0.f;
    w1t[i] = __builtin_bit_cast(unsigned short, __float2bfloat16(v));
}

static __device__ __forceinline__ unsigned int pack_bf16(float h0, float h1) {
#if __has_builtin(__builtin_amdgcn_cvt_pk_bf16_f32)
    return __builtin_bit_cast(unsigned int, __builtin_amdgcn_cvt_pk_bf16_f32(h0, h1));
#else
    unsigned int u0 = (unsigned int)__builtin_bit_cast(unsigned short, __float2bfloat16(h0));
    unsigned int u1 = (unsigned int)__builtin_bit_cast(unsigned short, __float2bfloat16(h1));
    return u0 | (u1 << 16);
#endif
}

// conv of k-band [K0, K0 + 8*NG) for this lane's sample; all indices compile-time
template<int K0, int NG>
static __device__ __forceinline__ void conv_band(const float* __restrict__ x,
        const float* __restrict__ wa, const float* __restrict__ ba,
        unsigned short* __restrict__ s_ha, int lane) {
    u32x4* row = reinterpret_cast<u32x4*>(s_ha + lane * HROW);   // 45 granules/row
    #pragma unroll
    for (int g = 0; g < NG; ++g) {
        unsigned int dw[4];
        #pragma unroll
        for (int e = 0; e < 4; ++e) {
            const int k0 = K0 + 8 * g + 2 * e;
            const int k1 = k0 + 1;
            float h0 = 0.f, h1 = 0.f;
            if (k0 < K1) {
                const int c = k0 / SPATIAL, ij = k0 % SPATIAL;
                h0 = fmaxf(fmaf(x[ij], wa[c], ba[c]), 0.f);
            }
            if (k1 < K1) {
                const int c = k1 / SPATIAL, ij = k1 % SPATIAL;
                h1 = fmaxf(fmaf(x[ij], wa[c], ba[c]), 0.f);
            }
            dw[e] = pack_bf16(h0, h1);
        }
        row[K0 / 8 + g] = (u32x4){dw[0], dw[1], dw[2], dw[3]};
    }
}

__global__ __launch_bounds__(512, 6)
void fused_actor_critic_mfma7(const float* __restrict__ state,
                              const float* __restrict__ wa, const float* __restrict__ ba,
                              const unsigned short* __restrict__ w1t, const float* __restrict__ b1,
                              const float* __restrict__ w2, const float* __restrict__ b2,
                              const float* __restrict__ wc, const float* __restrict__ bc,
                              const float* __restrict__ wlc, const float* __restrict__ blc,
                              float* __restrict__ out, int batch)
{
    // s_ha also serves as: (a) f32 staging rows at start, (b) FC2 partial buffer at end
    __shared__ __align__(16) unsigned short s_ha[TILE_M * HROW];   // 46080 B -> 3 blocks/CU
    // total 46080+tiny -> 51200-class footprint removed; 3 blk/CU = 24 waves

    const int t    = threadIdx.x;
    const int lane = t & 63;
    const int wave = t >> 6;         // 0..7
    const int lm   = lane & 15;
    const int lq   = lane >> 4;
    const int s_base = blockIdx.x * TILE_M;
    const int n0w  = wave * 32;      // 32 neurons per wave

    // ---- W prefetch: chunks 0,1 (contiguous 1KB/instr, L2-resident) ----
    bf16x8 wfr[2][2];
    const unsigned short* wrow = w1t + (size_t)(n0w + lm) * 32 + lq * 8;
    #pragma unroll
    for (int nt = 0; nt < 2; ++nt) wfr[0][nt] = *(const bf16x8*)(wrow + nt * 512);
    #pragma unroll
    for (int nt = 0; nt < 2; ++nt) wfr[1][nt] = *(const bf16x8*)(wrow + 8192 + nt * 512);

    // ---- stage state tile into s_ha-as-f32 (coalesced read, padded-row write) ----
    {
        float* sst = reinterpret_cast<float*>(s_ha);
        const float* src = state + (size_t)s_base * SPATIAL;
        #pragma unroll
        for (int r = 0; r < 5; ++r) {
            int idx = t + r * 512;
            if (idx < TILE_M * SPATIAL) {
                int s  = (int)(((unsigned)idx * 59919u) >> 21);    // idx/35, exact for idx<2240
                int ij = idx - s * SPATIAL;
                sst[s * SROW + ij] = src[idx];
            }
        }
    }
    __syncthreads();

    // ---- own sample row -> registers (transient) ----
    float x[36];
    {
        const f32x4* xr = reinterpret_cast<const f32x4*>(
            reinterpret_cast<const float*>(s_ha) + lane * SROW);
        #pragma unroll
        for (int q = 0; q < 9; ++q) *reinterpret_cast<f32x4*>(&x[4 * q]) = xr[q];
    }
    __syncthreads();      // all x loads done before conv overwrites the overlay

    // ---- cooperative conv: waves 0-6 own 48-k bands; wave 7: 16-k band + critic ----
    switch (wave) {
        case 0: conv_band<0,   6>(x, wa, ba, s_ha, lane); break;
        case 1: conv_band<48,  6>(x, wa, ba, s_ha, lane); break;
        case 2: conv_band<96,  6>(x, wa, ba, s_ha, lane); break;
        case 3: conv_band<144, 6>(x, wa, ba, s_ha, lane); break;
        case 4: conv_band<192, 6>(x, wa, ba, s_ha, lane); break;
        case 5: conv_band<240, 6>(x, wa, ba, s_ha, lane); break;
        case 6: conv_band<288, 6>(x, wa, ba, s_ha, lane); break;
        default: {
            conv_band<336, 2>(x, wa, ba, s_ha, lane);
            float cv = blc[0];
            #pragma unroll
            for (int ij = 0; ij < SPATIAL; ++ij)
                #pragma unroll
                for (int c = 0; c < 3; ++c)
                    cv = fmaf(wlc[c * SPATIAL + ij], fmaxf(fmaf(x[ij], wc[c], bc[c]), 0.f), cv);
            out[(size_t)5 * batch + s_base + lane] = cv;
            break;
        }
    }
    __syncthreads();

    // ---- barrier-free K loop: af depth-1 LDS prefetch, W depth-2 global prefetch ----
    f32x4 acc[2][4];                 // [nt][mt]; neuron = n0w+16nt+4lq+r, sample = 16mt+lm
    #pragma unroll
    for (int nt = 0; nt < 2; ++nt)
        #pragma unroll
        for (int mt = 0; mt < 4; ++mt)
            acc[nt][mt] = (f32x4){0.f, 0.f, 0.f, 0.f};

    const unsigned short* abase = s_ha + lm * HROW + lq * 8;
    bf16x8 afr[2][4];
    #pragma unroll
    for (int mt = 0; mt < 4; ++mt)
        afr[0][mt] = *(const bf16x8*)(abase + mt * 16 * HROW);

    #pragma unroll
    for (int ch = 0; ch < NCHUNK; ++ch) {
        if (ch + 1 < NCHUNK) {
            #pragma unroll
            for (int mt = 0; mt < 4; ++mt)
                afr[(ch + 1) & 1][mt] = *(const bf16x8*)(abase + mt * 16 * HROW + (ch + 1) * 32);
        }
        #pragma unroll
        for (int nt = 0; nt < 2; ++nt)
            #pragma unroll
            for (int mt = 0; mt < 4; ++mt)
                acc[nt][mt] = __builtin_amdgcn_mfma_f32_16x16x32_bf16(
                    wfr[ch & 1][nt], afr[ch & 1][mt], acc[nt][mt], 0, 0, 0);
        if (ch + 2 < NCHUNK) {
            #pragma unroll
            for (int nt = 0; nt < 2; ++nt)
                wfr[ch & 1][nt] = *(const bf16x8*)(wrow + (size_t)(ch + 2) * 8192 + nt * 512);
        }
    }

    // ---- bias + relu ----
    #pragma unroll
    for (int nt = 0; nt < 2; ++nt) {
        f32x4 bv = *(const f32x4*)&b1[n0w + 16 * nt + 4 * lq];
        #pragma unroll
        for (int mt = 0; mt < 4; ++mt)
            #pragma unroll
            for (int r = 0; r < 4; ++r)
                acc[nt][mt][r] = fmaxf(acc[nt][mt][r] + bv[r], 0.f);
    }

    __syncthreads();     // all af reads done; overlay s_ha as FC2 partial buffer
    float* part = reinterpret_cast<float*>(s_ha);    // [wave][m][l] : wave*320 + m*5 + l

    // ---- FC2: reduce over lq (2 shfl steps), partials to overlay ----
    #pragma unroll
    for (int l = 0; l < 5; ++l) {
        f32x4 wv[2];
        #pragma unroll
        for (int nt = 0; nt < 2; ++nt)
            wv[nt] = *(const f32x4*)&w2[l * N1 + n0w + 16 * nt + 4 * lq];
        #pragma unroll
        for (int mt = 0; mt < 4; ++mt) {
            float p = 0.f;
            #pragma unroll
            for (int nt = 0; nt < 2; ++nt)
                #pragma unroll
                for (int r = 0; r < 4; ++r)
                    p = fmaf(acc[nt][mt][r], wv[nt][r], p);
            p += __shfl_xor(p, 16);
            p += __shfl_xor(p, 32);
            bool mine = (l < 4) ? (lq == l) : (lq == 0);
            if (mine) part[wave * 320 + (16 * mt + lm) * 5 + l] = p;
        }
    }
    __syncthreads();

    // ---- final combine ----
    if (t < TILE_M) {
        const int gs = s_base + t;
        #pragma unroll
        for (int l = 0; l < 5; ++l) {
            float v = b2[l];
            #pragma unroll
            for (int w = 0; w < 8; ++w)
                v += part[w * 320 + t * 5 + l];
            out[(size_t)gs * 5 + l] = v;
        }
    }
}

extern "C" void kernel_launch(void* const* d_in, const int* in_sizes, int n_in,
                              void* d_out, int out_size, void* d_ws, size_t ws_size,
                              hipStream_t stream) {
    const float* state = (const float*)d_in[0];
    const float* wa    = (const float*)d_in[1];
    const float* ba    = (const float*)d_in[2];
    const float* w1    = (const float*)d_in[3];
    const float* b1    = (const float*)d_in[4];
    const float* w2    = (const float*)d_in[5];
    const float* b2    = (const float*)d_in[6];
    const float* wc    = (const float*)d_in[7];
    const float* bc    = (const float*)d_in[8];
    const float* wlc   = (const float*)d_in[9];
    const float* blc   = (const float*)d_in[10];
    float* out = (float*)d_out;
    unsigned short* w1t = (unsigned short*)d_ws;            // 180224 B

    int B = in_sizes[0] / SPATIAL;                          // 262144
    hipLaunchKernelGGL(convert_w1, dim3((N1 * KPAD) / 256), dim3(256), 0, stream, w1, w1t);
    hipLaunchKernelGGL(fused_actor_critic_mfma7, dim3(B / TILE_M), dim3(512), 0, stream,
                       state, wa, ba, w1t, b1, w2, b2, wc, bc, wlc, blc, out, B);
}